// Round 7
// baseline (514.242 us; speedup 1.0000x reference)
//
#include <hip/hip_runtime.h>

// TreecrfLossSRL: inside algorithm, B=64, N=256. Two CYK charts per batch
// (ob / allv) -> scalar (logz - marg).sum()/denom.
//
// LINEAR-DOMAIN chart with per-column scalar scale (exact cmax):
// col v stores X[v][i] = 2^(A[i,v] - cm[v]). Interior term of level L =
// 2^(cm[u]+cm[L-u]-b) * X[u][i] * X[L-u][i+u]  -> pure mul+fma hot loop.
// Group-of-8 levels; bulk (16 waves, 2/level) + flag-pipelined chain
// (wave g finalizes level W+g; producer: fence + LDS flag; consumer:
// volatile poll) -- r5/r6-proven structure kept verbatim.
//
// r6 -> r7:
//  1) BATCHED bulk loads: u processed in chunks of BT (4 for KK>=3, 8 for
//     KK<=2); all 2*BT*KK ds_reads issued back-to-back before the fma block
//     -> 8-32 outstanding LDS reads per wave (was ~4). At 16 waves/CU the
//     LDS pipe needs ~30 in flight to cover ~120cyc latency; r4-r6's
//     per-u loop ran bulk at >=2x its throughput floor. (r0's batch trick,
//     dropped in the r4 rewrite, restored.) VGPRs are free: LDS-bound
//     occupancy (1 block/CU) until 128 VGPR.
//  2) Chain poll backoff: fast first check, then s_sleep(1) loop -- polling
//     consumers stop stealing LDS issue slots from the producer spine.

#define NN 256
#define BATCH 64
#define NCHART (2 * BATCH)
#define NEGV -1000000000.0f
#define NEGB -1.0e30f
#define K2f 1.4426950408889634f   /* log2(e) */
#define LN2f 0.6931471805599453f

#define CHARTF 32896                   /* triangular chart, no padding */
#define CMAXF 260                      /* cmax[257] + pad */
#define BB_OFF (CHARTF + CMAXF)        /* per-group bases, 16 floats */
#define FLG_OFF (BB_OFF + 16)          /* 257 int flags (+pad) */
#define SCR_OFF (FLG_OFF + 260)
#define SCRF 3952                      /* 16 slots x ES, ES <= 247 */
#define LDSF (SCR_OFF + SCRF)          /* 37384 floats = 149536 B */

#define RES_OFF ((size_t)16)
#define LEN_OFF ((size_t)(16 + NCHART))
#define FB_OFF  ((size_t)(16 + NCHART + BATCH + 16))

__device__ __forceinline__ float fexp2(float x) {
#if __has_builtin(__builtin_amdgcn_exp2f)
    return __builtin_amdgcn_exp2f(x);
#else
    return exp2f(x);
#endif
}

// wave64 max reduce via DPP (VALU pipe), result broadcast to all lanes.
__device__ __forceinline__ float wave_max64(float x) {
    int v = __float_as_int(x);
    int s;
    s = __builtin_amdgcn_update_dpp(v, v, 0x111, 0xf, 0xf, false);
    v = __float_as_int(fmaxf(__int_as_float(v), __int_as_float(s)));
    s = __builtin_amdgcn_update_dpp(v, v, 0x112, 0xf, 0xf, false);
    v = __float_as_int(fmaxf(__int_as_float(v), __int_as_float(s)));
    s = __builtin_amdgcn_update_dpp(v, v, 0x114, 0xf, 0xf, false);
    v = __float_as_int(fmaxf(__int_as_float(v), __int_as_float(s)));
    s = __builtin_amdgcn_update_dpp(v, v, 0x118, 0xf, 0xf, false);
    v = __float_as_int(fmaxf(__int_as_float(v), __int_as_float(s)));
    s = __builtin_amdgcn_update_dpp(v, v, 0x142, 0xa, 0xf, false);
    v = __float_as_int(fmaxf(__int_as_float(v), __int_as_float(s)));
    s = __builtin_amdgcn_update_dpp(v, v, 0x143, 0xc, 0xf, false);
    v = __float_as_int(fmaxf(__int_as_float(v), __int_as_float(s)));
    return __int_as_float(__builtin_amdgcn_readlane(v, 63));
}

__device__ __forceinline__ float rlane(float v, int idx) {
    return __int_as_float(__builtin_amdgcn_readlane(__float_as_int(v), idx));
}

// column start (floats) for width v, v in 1..256
__device__ __forceinline__ int cstart(int v) {
    return 257 * (v - 1) - ((v * (v - 1)) >> 1);
}

// natural-log score at span [i, j] for type t (0 = ob/constrained, 1 = allv)
__device__ __forceinline__ float score_at(const float* __restrict__ logits,
                                          const int* __restrict__ spans_ind,
                                          const void* __restrict__ span_mask,
                                          int isb, int t, int b, int i, int j) {
    size_t sidx = ((size_t)b * NN + i) * NN + j;
    float l0 = logits[2 * sidx];
    float l1 = logits[2 * sidx + 1];
    if (t) {
        float mx = fmaxf(l0, l1), mn = fminf(l0, l1);
        return mx + log1pf(__expf(mn - mx));
    } else {
        bool sind = (spans_ind[sidx] == 2);
        bool sm = isb ? (((const unsigned char*)span_mask)[sidx] != 0)
                      : (((const int*)span_mask)[sidx] != 0);
        float s0 = (sm || sind)  ? NEGV : l0;
        float s1 = (sm || !sind) ? NEGV : l1;
        float mx = fmaxf(s0, s1), mn = fminf(s0, s1);
        return mx + log1pf(__expf(mn - mx));
    }
}

// group of 8 levels W..W+7; KK = ceil((257-W)/64)
template <int KK>
__device__ __forceinline__ void group8(
    float* __restrict__ Lc, float* __restrict__ scr, float* __restrict__ cm,
    float* __restrict__ bbuf, int* flg, float* __restrict__ sres,
    int W, int tid, int wave, int lane, int lenv) {
    const int ES = 257 - W;   // slot pitch = group max E
    constexpr int BT = (KK >= 3) ? 4 : 8;   // u-batch depth

    // ---------------- BULK: interior terms, 2 waves per level ----------
    {
        const int g = wave >> 1;
        const int half = wave & 1;
        const int L = W + g;
        if (L <= 256) {
            const int E = 257 - L;
            // base over full interior range (both halves -> same b)
            float b = NEGB;
            for (int uu = g + 1 + lane; uu <= W - 1; uu += 64)
                b = fmaxf(b, cm[uu] + cm[L - uu]);
            b = wave_max64(b);
            if (lane == 0 && half == 0) bbuf[g] = b;

            const int n_int = W - 1 - g;          // interior u-count
            const int h0 = (n_int + 1) >> 1;
            const int ua = half ? (g + 1 + h0) : (g + 1);
            const int ub = half ? (W - 1) : (g + h0);  // inclusive
            const int R = ub - ua + 1;                 // <= 125

            // split-scales in VGPRs (lane-parallel, readlane'd in the loop)
            float su0, su1 = 0.f;
            {
                int uu = ua + lane;
                int uc = (uu <= ub) ? uu : ub;
                su0 = fexp2(cm[uc] + cm[L - uc] - b);
                if (R > 64) {
                    int uu2 = ua + 64 + lane;
                    int uc2 = (uu2 <= ub) ? uu2 : ub;
                    su1 = fexp2(cm[uc2] + cm[L - uc2] - b);
                }
            }

            float acc[KK];
#pragma unroll
            for (int k = 0; k < KK; ++k) acc[k] = 0.f;

            if (R > 0) {
                int la = cstart(ua) + lane;
                int ra = cstart(L - ua) + ua + lane;
                int A = 257 - ua, B = 257 - (L - ua);
                int idx = 0;
                // batched main loop: issue all 2*BT*KK reads, then fma block
                for (; idx + BT <= R; idx += BT) {
                    int lqa[BT], rqa[BT];
                    float suq[BT];
                    int laq = la, raq = ra, As = A, Bs = B;
#pragma unroll
                    for (int q = 0; q < BT; ++q) {
                        lqa[q] = laq; rqa[q] = raq;
                        int iq = idx + q;
                        suq[q] = (iq < 64) ? rlane(su0, iq)
                                           : rlane(su1, iq - 64);
                        laq += As; As -= 1;
                        raq -= Bs; Bs += 1;
                    }
                    float lv[BT][KK], rv[BT][KK];
#pragma unroll
                    for (int q = 0; q < BT; ++q)
#pragma unroll
                        for (int k = 0; k < KK; ++k) {
                            lv[q][k] = Lc[lqa[q] + 64 * k];
                            rv[q][k] = Lc[rqa[q] + 64 * k];
                        }
#pragma unroll
                    for (int q = 0; q < BT; ++q)
#pragma unroll
                        for (int k = 0; k < KK; ++k)
                            acc[k] = fmaf(suq[q] * lv[q][k], rv[q][k], acc[k]);
                    la = laq; A = As; ra = raq; B = Bs;
                }
                // tail
                for (; idx < R; ++idx) {
                    float su = (idx < 64) ? rlane(su0, idx)
                                          : rlane(su1, idx - 64);
#pragma unroll
                    for (int k = 0; k < KK; ++k)
                        acc[k] = fmaf(su * Lc[la + 64 * k],
                                      Lc[ra + 64 * k], acc[k]);
                    la += A; A -= 1;
                    ra -= B; B += 1;
                }
            }
#pragma unroll
            for (int k = 0; k < KK; ++k) {
                int ge = lane + 64 * k;
                if (ge < E) scr[wave * ES + ge] = acc[k];
            }
        }
    }
    __syncthreads();   // G1: slots + bases ready

    // ------- CHAIN (pipelined): wave g finalizes level W+g, flag-synced ----
    if (wave < 8) {
        const int g = wave;
        const int L = W + g;
        if (L <= 256) {
            const int E = 257 - L;
            float m = bbuf[g];

            float s[KK];
#pragma unroll
            for (int k = 0; k < KK; ++k) {
                int ge = lane + 64 * k;
                s[k] = (ge < E) ? scr[(2 * g) * ES + ge] +
                                  scr[(2 * g + 1) * ES + ge]
                                : 0.f;
            }

            // border pairs in flag-arrival order: j=g (col W) .. j=1 (col L-1)
            for (int j = g; j >= 1; --j) {
                const int v = L - j;
                if (((volatile int*)flg)[v] == 0) {
                    do {
                        __builtin_amdgcn_s_sleep(1);
                    } while (((volatile int*)flg)[v] == 0);
                }
                asm volatile("" ::: "memory");   // acquire: no hoist above poll
                float pm = cm[j] + cm[v];
                float nm = fmaxf(m, pm);
                float sc = fexp2(m - nm), pj = fexp2(pm - nm);
                const int cj = cstart(j), cl = cstart(v);
#pragma unroll
                for (int k = 0; k < KK; ++k) {
                    int ge = lane + 64 * k;
                    if (ge < E) {
                        float tt = Lc[cj + ge] * Lc[cl + ge + j] +
                                   Lc[cl + ge] * Lc[cj + ge + v];
                        s[k] = fmaf(s[k], sc, pj * tt);
                    }
                }
                m = nm;
            }

            // finalize: a = D + m + log2(s); exact cmax intra-wave; X out
            float xa[KK];
            float mx = NEGB;
#pragma unroll
            for (int k = 0; k < KK; ++k) {
                int ge = lane + 64 * k;
                float av = NEGB;
                if (ge < E) av = Lc[cstart(L) + ge] + m + __log2f(s[k]);
                xa[k] = av;
                mx = fmaxf(mx, av);
            }
            mx = wave_max64(mx);
#pragma unroll
            for (int k = 0; k < KK; ++k) {
                int ge = lane + 64 * k;
                if (ge < E) Lc[cstart(L) + ge] = fexp2(xa[k] - mx);
            }
            if (lane == 0) {
                cm[L] = mx;
                if (L == lenv) *sres = xa[0];
            }
            __threadfence_block();               // release: drain col + cm
            asm volatile("" ::: "memory");
            if (lane == 0) ((volatile int*)flg)[L] = 1;
        }
    }
    __syncthreads();   // G2: group columns + cm final
}

// direct path for w in [2,9]: each thread does its entry's full sum
__device__ __forceinline__ void level_direct(
    float* __restrict__ Lc, float* __restrict__ cm,
    float* __restrict__ swm, float* __restrict__ sres,
    int w, int tid, int wave, int lane, int lenv) {
    const int E = NN + 1 - w;
    float a = NEGB;
    if (tid < E) {
        float b0 = NEGB;
        for (int u = 1; u <= w - 1; ++u) b0 = fmaxf(b0, cm[u] + cm[w - u]);
        float s = 0.f;
        for (int u = 1; u <= w - 1; ++u) {
            float su = fexp2(cm[u] + cm[w - u] - b0);
            s = fmaf(su * Lc[cstart(u) + tid], Lc[cstart(w - u) + u + tid], s);
        }
        int ad = cstart(w) + tid;
        a = Lc[ad] + b0 + __log2f(s);
        Lc[ad] = a;
        if (tid == 0 && w == lenv) *sres = a;
    }
    float m = wave_max64(a);
    if (lane == 0) swm[wave] = m;
    __syncthreads();
    float cmw = swm[0];
#pragma unroll
    for (int i = 1; i < 16; ++i) cmw = fmaxf(cmw, swm[i]);
    if (tid < E) {
        int ad = cstart(w) + tid;
        Lc[ad] = fexp2(Lc[ad] - cmw);
    }
    if (tid == 0) cm[w] = cmw;
    __syncthreads();
}

template <bool USE_LDS>
__global__ __launch_bounds__(1024) void cyk_kernel(
    const float* __restrict__ logits,     // [B,N,N,2] f32
    const int* __restrict__ spans_ind,    // [B,N,N] i32
    const void* __restrict__ maskspan,    // [B,N,N] bool (byte or i32)
    const void* __restrict__ span_mask,   // [B,N,N] bool
    float* __restrict__ ws) {
    extern __shared__ float lds[];
    const int c = blockIdx.x;
    const int b = c >> 1;
    const int t = c & 1;
    const int tid = threadIdx.x;
    const int wave = tid >> 6, lane = tid & 63;

    float* __restrict__ Lc = USE_LDS ? lds : (ws + FB_OFF + (size_t)c * LDSF);
    float* __restrict__ cm = Lc + CHARTF;
    float* __restrict__ bbuf = Lc + BB_OFF;
    int* flg = (int*)(Lc + FLG_OFF);
    float* __restrict__ scr = Lc + SCR_OFF;

    __shared__ int s_len;
    __shared__ int s_isb;
    __shared__ float s_wmax[16];
    __shared__ float s_res;
    if (tid == 0) {
        s_len = 0;
        s_res = K2f * NEGV;
        unsigned probe = *(const unsigned*)maskspan;
        s_isb = (probe > 1u) ? 1 : 0;  // byte-packed bools -> 0x01010101
    }
    if (tid < 260) flg[tid] = 0;       // per-level publish flags (set once)
    __syncthreads();
    const int isb = s_isb;

    // lens[b] = sum_j maskspan[b,0,j]
    if (tid < NN) {
        size_t off = (size_t)b * NN * NN + tid;
        int v = isb ? (((const unsigned char*)maskspan)[off] ? 1 : 0)
                    : (((const int*)maskspan)[off] ? 1 : 0);
        atomicAdd(&s_len, v);
    }

    // one-time D-fill: chart col v = j-i+1 holds K2f * D(i, v) until level v
    for (int it = 0; it < 64; ++it) {
        int f = (it << 10) + tid;            // over the (i, j) square
        int i = f >> 8, j = f & 255;
        if (j >= i) {
            float sc = score_at(logits, spans_ind, span_mask, isb, t, b, i, j);
            Lc[cstart(j - i + 1) + i] = K2f * sc;
        }
    }
    __syncthreads();
    const int lenv = s_len;

    // level 1: convert col 1 (= A[:,1]) to X with exact cmax[1]
    {
        float a = (tid < NN) ? Lc[tid] : NEGB;
        if (tid == 0 && lenv == 1) s_res = a;
        float m = wave_max64(a);
        if (lane == 0) s_wmax[wave] = m;
        __syncthreads();
        float c1 = s_wmax[0];
#pragma unroll
        for (int i = 1; i < 16; ++i) c1 = fmaxf(c1, s_wmax[i]);
        if (tid < NN) Lc[tid] = fexp2(a - c1);
        if (tid == 0) cm[1] = c1;
    }
    __syncthreads();

    for (int w = 2; w <= 9; ++w)
        level_direct(Lc, cm, s_wmax, &s_res, w, tid, wave, lane, lenv);
    for (int W = 10; W <= 58; W += 8)
        group8<4>(Lc, scr, cm, bbuf, flg, &s_res, W, tid, wave, lane, lenv);
    for (int W = 66; W <= 122; W += 8)
        group8<3>(Lc, scr, cm, bbuf, flg, &s_res, W, tid, wave, lane, lenv);
    for (int W = 130; W <= 186; W += 8)
        group8<2>(Lc, scr, cm, bbuf, flg, &s_res, W, tid, wave, lane, lenv);
    for (int W = 194; W <= 250; W += 8)
        group8<1>(Lc, scr, cm, bbuf, flg, &s_res, W, tid, wave, lane, lenv);

    if (tid == 0) {
        int len = s_len;
        float rres = (len >= 1) ? (s_res * LN2f) : NEGV;
        ws[RES_OFF + c] = rres;
        if (t == 0) ws[LEN_OFF + b] = (float)len;
    }
}

__global__ __launch_bounds__(64) void finish_kernel(const float* __restrict__ ws,
                                                    float* __restrict__ out) {
    int b = threadIdx.x;  // 0..63
    float diff = ws[RES_OFF + 2 * b + 1] - ws[RES_OFF + 2 * b];
    float len  = ws[LEN_OFF + b];
    for (int d = 32; d > 0; d >>= 1) {
        diff += __shfl_xor(diff, d);
        len  += __shfl_xor(len, d);
    }
    if (b == 0) out[0] = diff / len;
}

extern "C" void kernel_launch(void* const* d_in, const int* in_sizes, int n_in,
                              void* d_out, int out_size, void* d_ws, size_t ws_size,
                              hipStream_t stream) {
    const float* logits    = (const float*)d_in[0];
    const int*   spans_ind = (const int*)d_in[1];
    const void*  maskspan  = d_in[2];
    const void*  span_mask = d_in[3];
    float* ws = (float*)d_ws;

    const size_t shbytes = (size_t)LDSF * sizeof(float);  // 149536 B
    hipError_t e = hipFuncSetAttribute(
        reinterpret_cast<const void*>(&cyk_kernel<true>),
        hipFuncAttributeMaxDynamicSharedMemorySize, (int)shbytes);
    if (e == hipSuccess) {
        hipLaunchKernelGGL(cyk_kernel<true>, dim3(NCHART), dim3(1024), shbytes,
                           stream, logits, spans_ind, maskspan, span_mask, ws);
    } else {
        hipLaunchKernelGGL(cyk_kernel<false>, dim3(NCHART), dim3(1024), 0,
                           stream, logits, spans_ind, maskspan, span_mask, ws);
    }
    hipLaunchKernelGGL(finish_kernel, dim3(1), dim3(64), 0, stream,
                       ws, (float*)d_out);
}

// Round 8
// 476.462 us; speedup vs baseline: 1.0793x; 1.0793x over previous
//
#include <hip/hip_runtime.h>

// TreecrfLossSRL: inside algorithm, B=64, N=256. Two CYK charts per batch
// (ob / allv) -> scalar (logz - marg).sum()/denom.
//
// LINEAR-DOMAIN chart with per-column scalar scale (exact cmax):
// col v stores X[v][i] = 2^(A[i,v] - cm[v]). Interior term of level L =
// 2^(cm[u]+cm[L-u]-b) * X[u][i] * X[L-u][i+u]  -> pure mul+fma hot loop.
// Group-of-8 levels; bulk + flag-pipelined chain (wave g finalizes level
// W+g; producer: fence + LDS flag; consumer: tight volatile poll).
//
// r7 -> r8: r7's batching+sleep reverted (regressed: bulk is LDS-pipe
// THROUGHPUT-bound, ~123K ds_read_b32 wave-insts/block ~ 500-700K cyc of
// the 994K total; latency already covered by 16 waves). This round cuts
// bulk LDS traffic 25%: SHARED-LEFT LEVEL PAIRS (the r0-r3 trick, dropped
// in the r4 rewrite). 16 waves = 4 level-pairs x 4 u-splits; per u read
// left X[u][ge] once + two rights -> 3 reads / 2 terms. The 4 partials
// per level combine via r3's two-stage store+add (splits 2,3 store;
// barrier; splits 0,1 add) -> scratch stays 16 slots, chain unchanged.
// Per-level u-validity handled by zeroed split-scales.

#define NN 256
#define BATCH 64
#define NCHART (2 * BATCH)
#define NEGV -1000000000.0f
#define NEGB -1.0e30f
#define K2f 1.4426950408889634f   /* log2(e) */
#define LN2f 0.6931471805599453f

#define CHARTF 32896                   /* triangular chart, no padding */
#define CMAXF 260                      /* cmax[257] + pad */
#define BB_OFF (CHARTF + CMAXF)        /* per-group bases, 16 floats */
#define FLG_OFF (BB_OFF + 16)          /* 257 int flags (+pad) */
#define SCR_OFF (FLG_OFF + 260)
#define SCRF 3952                      /* 16 slots x ES, ES <= 247 */
#define LDSF (SCR_OFF + SCRF)          /* 37384 floats = 149536 B */

#define RES_OFF ((size_t)16)
#define LEN_OFF ((size_t)(16 + NCHART))
#define FB_OFF  ((size_t)(16 + NCHART + BATCH + 16))

__device__ __forceinline__ float fexp2(float x) {
#if __has_builtin(__builtin_amdgcn_exp2f)
    return __builtin_amdgcn_exp2f(x);
#else
    return exp2f(x);
#endif
}

// wave64 max reduce via DPP (VALU pipe), result broadcast to all lanes.
__device__ __forceinline__ float wave_max64(float x) {
    int v = __float_as_int(x);
    int s;
    s = __builtin_amdgcn_update_dpp(v, v, 0x111, 0xf, 0xf, false);
    v = __float_as_int(fmaxf(__int_as_float(v), __int_as_float(s)));
    s = __builtin_amdgcn_update_dpp(v, v, 0x112, 0xf, 0xf, false);
    v = __float_as_int(fmaxf(__int_as_float(v), __int_as_float(s)));
    s = __builtin_amdgcn_update_dpp(v, v, 0x114, 0xf, 0xf, false);
    v = __float_as_int(fmaxf(__int_as_float(v), __int_as_float(s)));
    s = __builtin_amdgcn_update_dpp(v, v, 0x118, 0xf, 0xf, false);
    v = __float_as_int(fmaxf(__int_as_float(v), __int_as_float(s)));
    s = __builtin_amdgcn_update_dpp(v, v, 0x142, 0xa, 0xf, false);
    v = __float_as_int(fmaxf(__int_as_float(v), __int_as_float(s)));
    s = __builtin_amdgcn_update_dpp(v, v, 0x143, 0xc, 0xf, false);
    v = __float_as_int(fmaxf(__int_as_float(v), __int_as_float(s)));
    return __int_as_float(__builtin_amdgcn_readlane(v, 63));
}

__device__ __forceinline__ float rlane(float v, int idx) {
    return __int_as_float(__builtin_amdgcn_readlane(__float_as_int(v), idx));
}

// column start (floats) for width v, v in 1..256
__device__ __forceinline__ int cstart(int v) {
    return 257 * (v - 1) - ((v * (v - 1)) >> 1);
}

// natural-log score at span [i, j] for type t (0 = ob/constrained, 1 = allv)
__device__ __forceinline__ float score_at(const float* __restrict__ logits,
                                          const int* __restrict__ spans_ind,
                                          const void* __restrict__ span_mask,
                                          int isb, int t, int b, int i, int j) {
    size_t sidx = ((size_t)b * NN + i) * NN + j;
    float l0 = logits[2 * sidx];
    float l1 = logits[2 * sidx + 1];
    if (t) {
        float mx = fmaxf(l0, l1), mn = fminf(l0, l1);
        return mx + log1pf(__expf(mn - mx));
    } else {
        bool sind = (spans_ind[sidx] == 2);
        bool sm = isb ? (((const unsigned char*)span_mask)[sidx] != 0)
                      : (((const int*)span_mask)[sidx] != 0);
        float s0 = (sm || sind)  ? NEGV : l0;
        float s1 = (sm || !sind) ? NEGV : l1;
        float mx = fmaxf(s0, s1), mn = fminf(s0, s1);
        return mx + log1pf(__expf(mn - mx));
    }
}

// group of 8 levels W..W+7; KK = ceil((257-W)/64)
template <int KK>
__device__ __forceinline__ void group8(
    float* __restrict__ Lc, float* __restrict__ scr, float* __restrict__ cm,
    float* __restrict__ bbuf, int* flg, float* __restrict__ sres,
    int W, int tid, int wave, int lane, int lenv) {
    const int ES = 257 - W;   // slot pitch = group max E

    // ---- BULK: 4 level-pairs x 4 u-splits, left operand shared in pair ----
    {
        const int p  = wave >> 2;        // pair 0..3
        const int sp = wave & 3;         // u-split 0..3
        const int g0 = 2 * p, g1 = g0 + 1;
        const int L0 = W + g0, L1 = W + g1;
        const bool has1 = (L1 <= 256);
        const int E0 = 257 - L0;
        const int E1 = has1 ? (257 - L1) : 0;

        // per-level bases over full interior (same value in all 4 splits)
        float b0 = NEGB, b1 = NEGB;
        for (int uu = g0 + 1 + lane; uu <= W - 1; uu += 64)
            b0 = fmaxf(b0, cm[uu] + cm[L0 - uu]);
        b0 = wave_max64(b0);
        if (has1) {
            for (int uu = g1 + 1 + lane; uu <= W - 1; uu += 64)
                b1 = fmaxf(b1, cm[uu] + cm[L1 - uu]);
            b1 = wave_max64(b1);
        }
        if (lane == 0 && sp == 0) {
            bbuf[g0] = b0;
            if (has1) bbuf[g1] = b1;
        }

        // this split's u-range within the union [g0+1, W-1]
        const int n = W - 1 - g0;              // union u-count (<= 247)
        const int C = (n + 3) >> 2;            // <= 62 -> one VGPR of scales
        const int ua = g0 + 1 + sp * C;
        const int ub = min(ua + C - 1, W - 1);
        const int R = ub - ua + 1;             // may be <= 0

        // split-scales in VGPRs; invalid terms get scale 0
        float su0r, su1r;
        {
            int u = ua + lane;
            int uc = (u <= ub) ? u : ub;       // safe clamp
            bool v0 = (lane < R);
            bool v1 = v0 && has1 && (uc >= g1 + 1);
            float e0 = fexp2(cm[uc] + cm[L0 - uc] - b0);
            float e1 = fexp2(cm[uc] + cm[L1 - uc] - b1);
            su0r = v0 ? e0 : 0.f;
            su1r = v1 ? e1 : 0.f;
        }

        float acc0[KK], acc1[KK];
#pragma unroll
        for (int k = 0; k < KK; ++k) { acc0[k] = 0.f; acc1[k] = 0.f; }

        if (R > 0) {
            int la  = cstart(ua) + lane;
            int ra0 = cstart(L0 - ua) + ua + lane;
            int ra1 = cstart(L1 - ua) + ua + lane;
            int A  = 257 - ua;
            int B0 = 257 - (L0 - ua);
            int B1 = 257 - (L1 - ua);
#pragma unroll 2
            for (int idx = 0; idx < R; ++idx) {
                float su0 = rlane(su0r, idx);
                float su1 = rlane(su1r, idx);
#pragma unroll
                for (int k = 0; k < KK; ++k) {
                    float lv = Lc[la  + 64 * k];
                    float r0 = Lc[ra0 + 64 * k];
                    float r1 = Lc[ra1 + 64 * k];
                    acc0[k] = fmaf(su0 * lv, r0, acc0[k]);
                    acc1[k] = fmaf(su1 * lv, r1, acc1[k]);
                }
                la += A; A -= 1;
                ra0 -= B0; B0 += 1;
                ra1 -= B1; B1 += 1;
            }
        }

        // two-stage combine into 16 slots (slot 2g+s for level g, sub s)
        const int s0 = 4 * p + (sp & 1);       // level g0 slot
        const int s1 = s0 + 2;                 // level g1 slot
        if (sp >= 2) {                         // stage 1: store
#pragma unroll
            for (int k = 0; k < KK; ++k) {
                int ge = lane + 64 * k;
                if (ge < E0) scr[s0 * ES + ge] = acc0[k];
                if (ge < E1) scr[s1 * ES + ge] = acc1[k];
            }
        }
        __syncthreads();   // B0: stage-1 slots initialized
        if (sp < 2) {                          // stage 2: accumulate
#pragma unroll
            for (int k = 0; k < KK; ++k) {
                int ge = lane + 64 * k;
                if (ge < E0) scr[s0 * ES + ge] += acc0[k];
                if (ge < E1) scr[s1 * ES + ge] += acc1[k];
            }
        }
    }
    __syncthreads();   // G1: slots + bases ready

    // ------- CHAIN (pipelined): wave g finalizes level W+g, flag-synced ----
    if (wave < 8) {
        const int g = wave;
        const int L = W + g;
        if (L <= 256) {
            const int E = 257 - L;
            float m = bbuf[g];

            float s[KK];
#pragma unroll
            for (int k = 0; k < KK; ++k) {
                int ge = lane + 64 * k;
                s[k] = (ge < E) ? scr[(2 * g) * ES + ge] +
                                  scr[(2 * g + 1) * ES + ge]
                                : 0.f;
            }

            // border pairs in flag-arrival order: j=g (col W) .. j=1 (col L-1)
            for (int j = g; j >= 1; --j) {
                const int v = L - j;
                while (((volatile int*)flg)[v] == 0) {}
                asm volatile("" ::: "memory");   // acquire: no hoist above poll
                float pm = cm[j] + cm[v];
                float nm = fmaxf(m, pm);
                float sc = fexp2(m - nm), pj = fexp2(pm - nm);
                const int cj = cstart(j), cl = cstart(v);
#pragma unroll
                for (int k = 0; k < KK; ++k) {
                    int ge = lane + 64 * k;
                    if (ge < E) {
                        float tt = Lc[cj + ge] * Lc[cl + ge + j] +
                                   Lc[cl + ge] * Lc[cj + ge + v];
                        s[k] = fmaf(s[k], sc, pj * tt);
                    }
                }
                m = nm;
            }

            // finalize: a = D + m + log2(s); exact cmax intra-wave; X out
            float xa[KK];
            float mx = NEGB;
#pragma unroll
            for (int k = 0; k < KK; ++k) {
                int ge = lane + 64 * k;
                float av = NEGB;
                if (ge < E) av = Lc[cstart(L) + ge] + m + __log2f(s[k]);
                xa[k] = av;
                mx = fmaxf(mx, av);
            }
            mx = wave_max64(mx);
#pragma unroll
            for (int k = 0; k < KK; ++k) {
                int ge = lane + 64 * k;
                if (ge < E) Lc[cstart(L) + ge] = fexp2(xa[k] - mx);
            }
            if (lane == 0) {
                cm[L] = mx;
                if (L == lenv) *sres = xa[0];
            }
            __threadfence_block();               // release: drain col + cm
            asm volatile("" ::: "memory");
            if (lane == 0) ((volatile int*)flg)[L] = 1;
        }
    }
    __syncthreads();   // G2: group columns + cm final
}

// direct path for w in [2,9]: each thread does its entry's full sum
__device__ __forceinline__ void level_direct(
    float* __restrict__ Lc, float* __restrict__ cm,
    float* __restrict__ swm, float* __restrict__ sres,
    int w, int tid, int wave, int lane, int lenv) {
    const int E = NN + 1 - w;
    float a = NEGB;
    if (tid < E) {
        float b0 = NEGB;
        for (int u = 1; u <= w - 1; ++u) b0 = fmaxf(b0, cm[u] + cm[w - u]);
        float s = 0.f;
        for (int u = 1; u <= w - 1; ++u) {
            float su = fexp2(cm[u] + cm[w - u] - b0);
            s = fmaf(su * Lc[cstart(u) + tid], Lc[cstart(w - u) + u + tid], s);
        }
        int ad = cstart(w) + tid;
        a = Lc[ad] + b0 + __log2f(s);
        Lc[ad] = a;
        if (tid == 0 && w == lenv) *sres = a;
    }
    float m = wave_max64(a);
    if (lane == 0) swm[wave] = m;
    __syncthreads();
    float cmw = swm[0];
#pragma unroll
    for (int i = 1; i < 16; ++i) cmw = fmaxf(cmw, swm[i]);
    if (tid < E) {
        int ad = cstart(w) + tid;
        Lc[ad] = fexp2(Lc[ad] - cmw);
    }
    if (tid == 0) cm[w] = cmw;
    __syncthreads();
}

template <bool USE_LDS>
__global__ __launch_bounds__(1024) void cyk_kernel(
    const float* __restrict__ logits,     // [B,N,N,2] f32
    const int* __restrict__ spans_ind,    // [B,N,N] i32
    const void* __restrict__ maskspan,    // [B,N,N] bool (byte or i32)
    const void* __restrict__ span_mask,   // [B,N,N] bool
    float* __restrict__ ws) {
    extern __shared__ float lds[];
    const int c = blockIdx.x;
    const int b = c >> 1;
    const int t = c & 1;
    const int tid = threadIdx.x;
    const int wave = tid >> 6, lane = tid & 63;

    float* __restrict__ Lc = USE_LDS ? lds : (ws + FB_OFF + (size_t)c * LDSF);
    float* __restrict__ cm = Lc + CHARTF;
    float* __restrict__ bbuf = Lc + BB_OFF;
    int* flg = (int*)(Lc + FLG_OFF);
    float* __restrict__ scr = Lc + SCR_OFF;

    __shared__ int s_len;
    __shared__ int s_isb;
    __shared__ float s_wmax[16];
    __shared__ float s_res;
    if (tid == 0) {
        s_len = 0;
        s_res = K2f * NEGV;
        unsigned probe = *(const unsigned*)maskspan;
        s_isb = (probe > 1u) ? 1 : 0;  // byte-packed bools -> 0x01010101
    }
    if (tid < 260) flg[tid] = 0;       // per-level publish flags (set once)
    __syncthreads();
    const int isb = s_isb;

    // lens[b] = sum_j maskspan[b,0,j]
    if (tid < NN) {
        size_t off = (size_t)b * NN * NN + tid;
        int v = isb ? (((const unsigned char*)maskspan)[off] ? 1 : 0)
                    : (((const int*)maskspan)[off] ? 1 : 0);
        atomicAdd(&s_len, v);
    }

    // one-time D-fill: chart col v = j-i+1 holds K2f * D(i, v) until level v
    for (int it = 0; it < 64; ++it) {
        int f = (it << 10) + tid;            // over the (i, j) square
        int i = f >> 8, j = f & 255;
        if (j >= i) {
            float sc = score_at(logits, spans_ind, span_mask, isb, t, b, i, j);
            Lc[cstart(j - i + 1) + i] = K2f * sc;
        }
    }
    __syncthreads();
    const int lenv = s_len;

    // level 1: convert col 1 (= A[:,1]) to X with exact cmax[1]
    {
        float a = (tid < NN) ? Lc[tid] : NEGB;
        if (tid == 0 && lenv == 1) s_res = a;
        float m = wave_max64(a);
        if (lane == 0) s_wmax[wave] = m;
        __syncthreads();
        float c1 = s_wmax[0];
#pragma unroll
        for (int i = 1; i < 16; ++i) c1 = fmaxf(c1, s_wmax[i]);
        if (tid < NN) Lc[tid] = fexp2(a - c1);
        if (tid == 0) cm[1] = c1;
    }
    __syncthreads();

    for (int w = 2; w <= 9; ++w)
        level_direct(Lc, cm, s_wmax, &s_res, w, tid, wave, lane, lenv);
    for (int W = 10; W <= 58; W += 8)
        group8<4>(Lc, scr, cm, bbuf, flg, &s_res, W, tid, wave, lane, lenv);
    for (int W = 66; W <= 122; W += 8)
        group8<3>(Lc, scr, cm, bbuf, flg, &s_res, W, tid, wave, lane, lenv);
    for (int W = 130; W <= 186; W += 8)
        group8<2>(Lc, scr, cm, bbuf, flg, &s_res, W, tid, wave, lane, lenv);
    for (int W = 194; W <= 250; W += 8)
        group8<1>(Lc, scr, cm, bbuf, flg, &s_res, W, tid, wave, lane, lenv);

    if (tid == 0) {
        int len = s_len;
        float rres = (len >= 1) ? (s_res * LN2f) : NEGV;
        ws[RES_OFF + c] = rres;
        if (t == 0) ws[LEN_OFF + b] = (float)len;
    }
}

__global__ __launch_bounds__(64) void finish_kernel(const float* __restrict__ ws,
                                                    float* __restrict__ out) {
    int b = threadIdx.x;  // 0..63
    float diff = ws[RES_OFF + 2 * b + 1] - ws[RES_OFF + 2 * b];
    float len  = ws[LEN_OFF + b];
    for (int d = 32; d > 0; d >>= 1) {
        diff += __shfl_xor(diff, d);
        len  += __shfl_xor(len, d);
    }
    if (b == 0) out[0] = diff / len;
}

extern "C" void kernel_launch(void* const* d_in, const int* in_sizes, int n_in,
                              void* d_out, int out_size, void* d_ws, size_t ws_size,
                              hipStream_t stream) {
    const float* logits    = (const float*)d_in[0];
    const int*   spans_ind = (const int*)d_in[1];
    const void*  maskspan  = d_in[2];
    const void*  span_mask = d_in[3];
    float* ws = (float*)d_ws;

    const size_t shbytes = (size_t)LDSF * sizeof(float);  // 149536 B
    hipError_t e = hipFuncSetAttribute(
        reinterpret_cast<const void*>(&cyk_kernel<true>),
        hipFuncAttributeMaxDynamicSharedMemorySize, (int)shbytes);
    if (e == hipSuccess) {
        hipLaunchKernelGGL(cyk_kernel<true>, dim3(NCHART), dim3(1024), shbytes,
                           stream, logits, spans_ind, maskspan, span_mask, ws);
    } else {
        hipLaunchKernelGGL(cyk_kernel<false>, dim3(NCHART), dim3(1024), 0,
                           stream, logits, spans_ind, maskspan, span_mask, ws);
    }
    hipLaunchKernelGGL(finish_kernel, dim3(1), dim3(64), 0, stream,
                       ws, (float*)d_out);
}

// Round 9
// 420.901 us; speedup vs baseline: 1.2218x; 1.1320x over previous
//
#include <hip/hip_runtime.h>

// TreecrfLossSRL: inside algorithm, B=64, N=256. Two CYK charts per batch
// (ob / allv) -> scalar (logz - marg).sum()/denom.
//
// LINEAR-DOMAIN chart, per-column exact scale cm[v]; X[v][i]=2^(A-cm).
// r8 -> r9: CHAIN/PRE-BULK OVERLAP. Per group (8 levels, base W), interior
// split by operand age:
//   pre    u in [g+9, W-9]            both cols < W  -> computed by waves
//          8..15 DURING THE PREVIOUS GROUP'S CHAIN (shared-left pairs,
//          r8 skeleton) into parity-alternating slots + bases.
//   fixup  u in [g+1,min(g+8,W-1)] U [max(W-8,g+9),W-1]  one col in the
//          just-finished group -> chain wave g computes itself (inputs
//          barrier-guaranteed, no polls), single rescale + plain fma adds.
//   border u in [1,g] U [W,L-1]       in-group cols -> r8 flag-synced fold.
// No separate bulk phase: each group = {chain waves 0-7 || pre waves 8-15}
// + ONE __syncthreads. Chain (~150K cyc serial) hides under pre-bulk LDS.
// Statics moved into dynamic LDS; total 163,796 B (fits 160 KiB).

#define NN 256
#define BATCH 64
#define NCHART (2 * BATCH)
#define NEGV -1000000000.0f
#define NEGB -1.0e30f
#define K2f 1.4426950408889634f   /* log2(e) */
#define LN2f 0.6931471805599453f

// LDS layout (float offsets)
#define CM_OFF  32896              /* cm[257] */
#define BB_OFF  (CM_OFF + 257)     /* 16: bases (2x8 parity); swm in direct */
#define FLG_OFF (BB_OFF + 16)      /* 257 int flags */
#define MSC_OFF (FLG_OFF + 257)    /* [0] len, [1] isb, [2] res(float) */
#define S0_OFF  (MSC_OFF + 3)      /* 3696 = 16*231 (even-index groups) */
#define S1_OFF  (S0_OFF + 3696)    /* 3824 = 16*239 (odd-index groups)  */
#define LDSF    (S1_OFF + 3824)    /* 40949 floats = 163796 B */

#define RES_OFF ((size_t)16)
#define LEN_OFF ((size_t)(16 + NCHART))
#define FB_OFF  ((size_t)(16 + NCHART + BATCH + 16))

__device__ __forceinline__ float fexp2(float x) {
#if __has_builtin(__builtin_amdgcn_exp2f)
    return __builtin_amdgcn_exp2f(x);
#else
    return exp2f(x);
#endif
}

// wave64 max reduce via DPP (VALU pipe), broadcast via readlane 63.
__device__ __forceinline__ float wave_max64(float x) {
    int v = __float_as_int(x);
    int s;
    s = __builtin_amdgcn_update_dpp(v, v, 0x111, 0xf, 0xf, false);
    v = __float_as_int(fmaxf(__int_as_float(v), __int_as_float(s)));
    s = __builtin_amdgcn_update_dpp(v, v, 0x112, 0xf, 0xf, false);
    v = __float_as_int(fmaxf(__int_as_float(v), __int_as_float(s)));
    s = __builtin_amdgcn_update_dpp(v, v, 0x114, 0xf, 0xf, false);
    v = __float_as_int(fmaxf(__int_as_float(v), __int_as_float(s)));
    s = __builtin_amdgcn_update_dpp(v, v, 0x118, 0xf, 0xf, false);
    v = __float_as_int(fmaxf(__int_as_float(v), __int_as_float(s)));
    s = __builtin_amdgcn_update_dpp(v, v, 0x142, 0xa, 0xf, false);
    v = __float_as_int(fmaxf(__int_as_float(v), __int_as_float(s)));
    s = __builtin_amdgcn_update_dpp(v, v, 0x143, 0xc, 0xf, false);
    v = __float_as_int(fmaxf(__int_as_float(v), __int_as_float(s)));
    return __int_as_float(__builtin_amdgcn_readlane(v, 63));
}

__device__ __forceinline__ float rlane(float v, int idx) {
    return __int_as_float(__builtin_amdgcn_readlane(__float_as_int(v), idx));
}

// column start (floats) for width v, v in 1..256
__device__ __forceinline__ int cstart(int v) {
    return 257 * (v - 1) - ((v * (v - 1)) >> 1);
}

// natural-log score at span [i, j] for type t (0 = ob/constrained, 1 = allv)
__device__ __forceinline__ float score_at(const float* __restrict__ logits,
                                          const int* __restrict__ spans_ind,
                                          const void* __restrict__ span_mask,
                                          int isb, int t, int b, int i, int j) {
    size_t sidx = ((size_t)b * NN + i) * NN + j;
    float l0 = logits[2 * sidx];
    float l1 = logits[2 * sidx + 1];
    if (t) {
        float mx = fmaxf(l0, l1), mn = fminf(l0, l1);
        return mx + log1pf(__expf(mn - mx));
    } else {
        bool sind = (spans_ind[sidx] == 2);
        bool sm = isb ? (((const unsigned char*)span_mask)[sidx] != 0)
                      : (((const int*)span_mask)[sidx] != 0);
        float s0 = (sm || sind)  ? NEGV : l0;
        float s1 = (sm || !sind) ? NEGV : l1;
        float mx = fmaxf(s0, s1), mn = fminf(s0, s1);
        return mx + log1pf(__expf(mn - mx));
    }
}

// One group (levels W..W+7): chain waves 0..7 finalize; waves 8..15 pre-bulk
// the NEXT group (W+8) into scrW/bbW. KK = ceil((257-W)/64), KK2 for next.
template <int KK, int KK2>
__device__ __forceinline__ void group_olap(
    float* __restrict__ Lc, float* __restrict__ cm, int* flg, int* msc,
    const float* __restrict__ scrR, float* __restrict__ scrW,
    const float* __restrict__ bbR, float* __restrict__ bbW,
    int W, int wave, int lane, int lenv) {
    const int ESR = 257 - W;

    if (wave >= 8) {
        if constexpr (KK2 > 0) {
            // ---- PRE-BULK for group W2 = W+8: 4 pairs x 2 u-splits ----
            const int W2 = W + 8;
            const int ESW = 257 - W2;
            const int p = (wave - 8) >> 1, sp = (wave - 8) & 1;
            const int G0 = 2 * p, G1 = G0 + 1;
            const int L0 = W2 + G0, L1 = W2 + G1;
            const bool has1 = (L1 <= 256);
            const int E0 = 257 - L0;
            const int E1 = has1 ? (257 - L1) : 0;
            const int lo0 = G0 + 9, hi = W2 - 9;   // hi = W-1: cols stable

            float b0 = NEGB, b1 = NEGB;
            for (int uu = lo0 + lane; uu <= hi; uu += 64) {
                float cu = cm[uu];
                b0 = fmaxf(b0, cu + cm[L0 - uu]);
                if (uu >= lo0 + 1) b1 = fmaxf(b1, cu + cm[L1 - uu]);
            }
            b0 = wave_max64(b0);
            b1 = wave_max64(b1);
            if (lane == 0 && sp == 0) { bbW[G0] = b0; bbW[G1] = b1; }

            const int n = hi - lo0 + 1;
            if (n > 0) {
                const int C = (n + 1) >> 1;
                const int ua = lo0 + sp * C;
                const int ub = min(ua + C - 1, hi);
                const int R = ub - ua + 1;       // <= 121

                float su0r, su1r;
                {
                    int u = ua + lane;
                    int uc = (u <= ub) ? u : ub;
                    bool v0 = (lane < R);
                    bool v1 = v0 && has1 && (uc >= lo0 + 1);
                    float e0 = fexp2(cm[uc] + cm[L0 - uc] - b0);
                    float e1 = fexp2(cm[uc] + cm[L1 - uc] - b1);
                    su0r = v0 ? e0 : 0.f;
                    su1r = v1 ? e1 : 0.f;
                }
                float su2r = 0.f, su3r = 0.f;
                if (R > 64) {
                    int u = ua + 64 + lane;
                    int uc = (u <= ub) ? u : ub;
                    bool v0 = (64 + lane < R);
                    bool v1 = v0 && has1;
                    float e0 = fexp2(cm[uc] + cm[L0 - uc] - b0);
                    float e1 = fexp2(cm[uc] + cm[L1 - uc] - b1);
                    su2r = v0 ? e0 : 0.f;
                    su3r = v1 ? e1 : 0.f;
                }

                float a0[KK2], a1[KK2];
#pragma unroll
                for (int k = 0; k < KK2; ++k) { a0[k] = 0.f; a1[k] = 0.f; }

                if (R > 0) {
                    int la  = cstart(ua) + lane;
                    int ra0 = cstart(L0 - ua) + ua + lane;
                    int ra1 = cstart(L1 - ua) + ua + lane;
                    int A  = 257 - ua;
                    int B0 = 257 - (L0 - ua);
                    int B1 = 257 - (L1 - ua);
                    const int R0 = (R < 64) ? R : 64;
#pragma unroll 2
                    for (int idx = 0; idx < R0; ++idx) {
                        float su0 = rlane(su0r, idx);
                        float su1 = rlane(su1r, idx);
#pragma unroll
                        for (int k = 0; k < KK2; ++k) {
                            float lv = Lc[la  + 64 * k];
                            float r0 = Lc[ra0 + 64 * k];
                            float r1 = Lc[ra1 + 64 * k];
                            a0[k] = fmaf(su0 * lv, r0, a0[k]);
                            a1[k] = fmaf(su1 * lv, r1, a1[k]);
                        }
                        la += A; A -= 1;
                        ra0 -= B0; B0 += 1;
                        ra1 -= B1; B1 += 1;
                    }
#pragma unroll 2
                    for (int idx = 64; idx < R; ++idx) {
                        float su0 = rlane(su2r, idx - 64);
                        float su1 = rlane(su3r, idx - 64);
#pragma unroll
                        for (int k = 0; k < KK2; ++k) {
                            float lv = Lc[la  + 64 * k];
                            float r0 = Lc[ra0 + 64 * k];
                            float r1 = Lc[ra1 + 64 * k];
                            a0[k] = fmaf(su0 * lv, r0, a0[k]);
                            a1[k] = fmaf(su1 * lv, r1, a1[k]);
                        }
                        la += A; A -= 1;
                        ra0 -= B0; B0 += 1;
                        ra1 -= B1; B1 += 1;
                    }
                }
#pragma unroll
                for (int k = 0; k < KK2; ++k) {
                    int ge = lane + 64 * k;
                    if (ge < E0) scrW[(2 * G0 + sp) * ESW + ge] = a0[k];
                    if (ge < E1) scrW[(2 * G1 + sp) * ESW + ge] = a1[k];
                }
            }
        }
    } else {
        // ---- CHAIN: wave g finalizes level W+g (fixup + borders) ----
        const int g = wave;
        const int L = W + g;
        if (L <= 256) {
            const int E = 257 - L;
            float m = NEGB;
            float s[KK];
#pragma unroll
            for (int k = 0; k < KK; ++k) s[k] = 0.f;

            if (W >= g + 18) {                  // pre-band existed
                m = bbR[g];
#pragma unroll
                for (int k = 0; k < KK; ++k) {
                    int ge = lane + 64 * k;
                    if (ge < E)
                        s[k] = scrR[(2 * g) * ESR + ge] +
                               scrR[(2 * g + 1) * ESR + ge];
                }
            }

            // fixup bands (operand in previous group; barrier-guaranteed)
            const int b1lo = g + 1, b1hi = min(g + 8, W - 1);
            const int b2lo = max(W - 8, g + 9), b2hi = W - 1;
            float m2 = m;
            for (int u = b1lo; u <= b1hi; ++u) m2 = fmaxf(m2, cm[u] + cm[L - u]);
            for (int u = b2lo; u <= b2hi; ++u) m2 = fmaxf(m2, cm[u] + cm[L - u]);
            {
                float sc = fexp2(m - m2);
#pragma unroll
                for (int k = 0; k < KK; ++k) s[k] *= sc;
                m = m2;
            }
            for (int u = b1lo; u <= b1hi; ++u) {
                float su = fexp2(cm[u] + cm[L - u] - m);
                const int ca = cstart(u), cb = cstart(L - u);
#pragma unroll
                for (int k = 0; k < KK; ++k) {
                    int ge = lane + 64 * k;
                    if (ge < E)
                        s[k] = fmaf(su * Lc[ca + ge], Lc[cb + ge + u], s[k]);
                }
            }
            for (int u = b2lo; u <= b2hi; ++u) {
                float su = fexp2(cm[u] + cm[L - u] - m);
                const int ca = cstart(u), cb = cstart(L - u);
#pragma unroll
                for (int k = 0; k < KK; ++k) {
                    int ge = lane + 64 * k;
                    if (ge < E)
                        s[k] = fmaf(su * Lc[ca + ge], Lc[cb + ge + u], s[k]);
                }
            }

            // borders j=g..1 (flag-synced, r8 verbatim)
            for (int j = g; j >= 1; --j) {
                const int v = L - j;
                while (((volatile int*)flg)[v] == 0) {}
                asm volatile("" ::: "memory");
                float pm = cm[j] + cm[v];
                float nm = fmaxf(m, pm);
                float sc = fexp2(m - nm), pj = fexp2(pm - nm);
                const int cj = cstart(j), cl = cstart(v);
#pragma unroll
                for (int k = 0; k < KK; ++k) {
                    int ge = lane + 64 * k;
                    if (ge < E) {
                        float tt = Lc[cj + ge] * Lc[cl + ge + j] +
                                   Lc[cl + ge] * Lc[cj + ge + v];
                        s[k] = fmaf(s[k], sc, pj * tt);
                    }
                }
                m = nm;
            }

            // finalize: a = D + m + log2(s); exact cmax; publish X + flag
            float xa[KK];
            float mx = NEGB;
#pragma unroll
            for (int k = 0; k < KK; ++k) {
                int ge = lane + 64 * k;
                float av = NEGB;
                if (ge < E) av = Lc[cstart(L) + ge] + m + __log2f(s[k]);
                xa[k] = av;
                mx = fmaxf(mx, av);
            }
            mx = wave_max64(mx);
#pragma unroll
            for (int k = 0; k < KK; ++k) {
                int ge = lane + 64 * k;
                if (ge < E) Lc[cstart(L) + ge] = fexp2(xa[k] - mx);
            }
            if (lane == 0) {
                cm[L] = mx;
                if (L == lenv) ((float*)msc)[2] = xa[0];
            }
            __threadfence_block();
            asm volatile("" ::: "memory");
            if (lane == 0) ((volatile int*)flg)[L] = 1;
        }
    }
    __syncthreads();   // group columns + cm + next-group slots visible
}

// direct path for w in [2,9]
__device__ __forceinline__ void level_direct(
    float* __restrict__ Lc, float* __restrict__ cm,
    float* __restrict__ swm, int* msc,
    int w, int tid, int wave, int lane, int lenv) {
    const int E = NN + 1 - w;
    float a = NEGB;
    if (tid < E) {
        float b0 = NEGB;
        for (int u = 1; u <= w - 1; ++u) b0 = fmaxf(b0, cm[u] + cm[w - u]);
        float s = 0.f;
        for (int u = 1; u <= w - 1; ++u) {
            float su = fexp2(cm[u] + cm[w - u] - b0);
            s = fmaf(su * Lc[cstart(u) + tid], Lc[cstart(w - u) + u + tid], s);
        }
        int ad = cstart(w) + tid;
        a = Lc[ad] + b0 + __log2f(s);
        Lc[ad] = a;
        if (tid == 0 && w == lenv) ((float*)msc)[2] = a;
    }
    float m = wave_max64(a);
    if (lane == 0) swm[wave] = m;
    __syncthreads();
    float cmw = swm[0];
#pragma unroll
    for (int i = 1; i < 16; ++i) cmw = fmaxf(cmw, swm[i]);
    if (tid < E) {
        int ad = cstart(w) + tid;
        Lc[ad] = fexp2(Lc[ad] - cmw);
    }
    if (tid == 0) cm[w] = cmw;
    __syncthreads();
}

template <bool USE_LDS>
__global__ __launch_bounds__(1024) void cyk_kernel(
    const float* __restrict__ logits,     // [B,N,N,2] f32
    const int* __restrict__ spans_ind,    // [B,N,N] i32
    const void* __restrict__ maskspan,    // [B,N,N] bool (byte or i32)
    const void* __restrict__ span_mask,   // [B,N,N] bool
    float* __restrict__ ws) {
    extern __shared__ float lds[];
    const int c = blockIdx.x;
    const int b = c >> 1;
    const int t = c & 1;
    const int tid = threadIdx.x;
    const int wave = tid >> 6, lane = tid & 63;

    float* __restrict__ Lc = USE_LDS ? lds : (ws + FB_OFF + (size_t)c * LDSF);
    float* __restrict__ cm = Lc + CM_OFF;
    float* __restrict__ BB = Lc + BB_OFF;
    int* flg = (int*)(Lc + FLG_OFF);
    int* msc = (int*)(Lc + MSC_OFF);
    float* __restrict__ S0 = Lc + S0_OFF;
    float* __restrict__ S1 = Lc + S1_OFF;

    if (tid == 0) {
        ((float*)msc)[2] = K2f * NEGV;
        unsigned probe = *(const unsigned*)maskspan;
        msc[1] = (probe > 1u) ? 1 : 0;  // byte-packed bools -> 0x01010101
    }
    if (tid < 257) flg[tid] = 0;
    __syncthreads();
    const int isb = msc[1];

    // lens[b]: wave 0 counts 256 mask entries (4/lane), shfl-sum
    if (wave == 0) {
        int cnt = 0;
        for (int q = 0; q < 4; ++q) {
            int j = lane * 4 + q;
            size_t off = (size_t)b * NN * NN + j;
            int v = isb ? (((const unsigned char*)maskspan)[off] ? 1 : 0)
                        : (((const int*)maskspan)[off] ? 1 : 0);
            cnt += v;
        }
        for (int d = 32; d; d >>= 1) cnt += __shfl_xor(cnt, d);
        if (lane == 0) msc[0] = cnt;
    }

    // one-time D-fill: chart col v = j-i+1 holds K2f * D(i, v) until level v
    for (int it = 0; it < 64; ++it) {
        int f = (it << 10) + tid;            // over the (i, j) square
        int i = f >> 8, j = f & 255;
        if (j >= i) {
            float sc = score_at(logits, spans_ind, span_mask, isb, t, b, i, j);
            Lc[cstart(j - i + 1) + i] = K2f * sc;
        }
    }
    __syncthreads();
    const int lenv = msc[0];

    // level 1: convert col 1 to X with exact cmax[1]
    {
        float a = (tid < NN) ? Lc[tid] : NEGB;
        if (tid == 0 && lenv == 1) ((float*)msc)[2] = a;
        float m = wave_max64(a);
        if (lane == 0) BB[wave] = m;
        __syncthreads();
        float c1 = BB[0];
#pragma unroll
        for (int i = 1; i < 16; ++i) c1 = fmaxf(c1, BB[i]);
        if (tid < NN) Lc[tid] = fexp2(a - c1);
        if (tid == 0) cm[1] = c1;
    }
    __syncthreads();

    for (int w = 2; w <= 9; ++w)
        level_direct(Lc, cm, BB, msc, w, tid, wave, lane, lenv);

    // groups: W = 10 + 8k; group k reads buf[k&1], writes buf[(k+1)&1]
#define GRP(KA, KB, WV)                                                     \
    {                                                                       \
        const int gk = ((WV) - 10) >> 3;                                    \
        const float* sR = (gk & 1) ? S1 : S0;                               \
        float* sW = (gk & 1) ? S0 : S1;                                     \
        const float* bR = BB + (gk & 1) * 8;                                \
        float* bW = BB + ((gk + 1) & 1) * 8;                                \
        group_olap<KA, KB>(Lc, cm, flg, msc, sR, sW, bR, bW, (WV),          \
                           wave, lane, lenv);                               \
    }
    for (int W = 10; W <= 50; W += 8) GRP(4, 4, W)
    GRP(4, 3, 58)
    for (int W = 66; W <= 114; W += 8) GRP(3, 3, W)
    GRP(3, 2, 122)
    for (int W = 130; W <= 178; W += 8) GRP(2, 2, W)
    GRP(2, 1, 186)
    for (int W = 194; W <= 242; W += 8) GRP(1, 1, W)
    GRP(1, 0, 250)
#undef GRP

    if (tid == 0) {
        int len = msc[0];
        float rres = (len >= 1) ? (((float*)msc)[2] * LN2f) : NEGV;
        ws[RES_OFF + c] = rres;
        if (t == 0) ws[LEN_OFF + b] = (float)len;
    }
}

__global__ __launch_bounds__(64) void finish_kernel(const float* __restrict__ ws,
                                                    float* __restrict__ out) {
    int b = threadIdx.x;  // 0..63
    float diff = ws[RES_OFF + 2 * b + 1] - ws[RES_OFF + 2 * b];
    float len  = ws[LEN_OFF + b];
    for (int d = 32; d > 0; d >>= 1) {
        diff += __shfl_xor(diff, d);
        len  += __shfl_xor(len, d);
    }
    if (b == 0) out[0] = diff / len;
}

extern "C" void kernel_launch(void* const* d_in, const int* in_sizes, int n_in,
                              void* d_out, int out_size, void* d_ws, size_t ws_size,
                              hipStream_t stream) {
    const float* logits    = (const float*)d_in[0];
    const int*   spans_ind = (const int*)d_in[1];
    const void*  maskspan  = d_in[2];
    const void*  span_mask = d_in[3];
    float* ws = (float*)d_ws;

    const size_t shbytes = (size_t)LDSF * sizeof(float);  // 163796 B
    hipError_t e = hipFuncSetAttribute(
        reinterpret_cast<const void*>(&cyk_kernel<true>),
        hipFuncAttributeMaxDynamicSharedMemorySize, (int)shbytes);
    if (e == hipSuccess) {
        hipLaunchKernelGGL(cyk_kernel<true>, dim3(NCHART), dim3(1024), shbytes,
                           stream, logits, spans_ind, maskspan, span_mask, ws);
    } else {
        hipLaunchKernelGGL(cyk_kernel<false>, dim3(NCHART), dim3(1024), 0,
                           stream, logits, spans_ind, maskspan, span_mask, ws);
    }
    hipLaunchKernelGGL(finish_kernel, dim3(1), dim3(64), 0, stream,
                       ws, (float*)d_out);
}

// Round 10
// 393.744 us; speedup vs baseline: 1.3060x; 1.0690x over previous
//
#include <hip/hip_runtime.h>

// TreecrfLossSRL: inside algorithm, B=64, N=256. Two CYK charts per batch
// (ob / allv) -> scalar (logz - marg).sum()/denom.
//
// LINEAR-DOMAIN chart, per-column exact scale cm[v]; X[v][i]=2^(A-cm).
// Group-of-8 levels; chain (waves 0-7, flag-pipelined, wave g = level W+g)
// runs CONCURRENTLY with pre-bulk (waves 8-15 computing the NEXT group's
// interior band into parity-alternating slots). One barrier per group.
//
// r9 -> r10:
//  1) SEED-CHAIN: levels 2..9 now flag-pipelined (wave g -> level g+2,
//     border-pair folding, self-pair guard for even L). Replaces 8x
//     level_direct: 16 barriers + 8 serial phases -> 1 barrier.
//  2) BORDER HOIST: chain border loop issues the ancient-column (j<=7,
//     seed-era) reads BEFORE the flag poll -> halves post-poll LDS on the
//     level-to-level critical path.
//  3) HW-SOFTPLUS D-fill: log1pf(expf) -> log2(1+2^x) in log2 domain
//     (identical limiting behavior; drops the library log1pf).

#define NN 256
#define BATCH 64
#define NCHART (2 * BATCH)
#define NEGV -1000000000.0f
#define NEGB -1.0e30f
#define K2f 1.4426950408889634f   /* log2(e) */
#define LN2f 0.6931471805599453f

// LDS layout (float offsets)
#define CM_OFF  32896              /* cm[257] */
#define BB_OFF  (CM_OFF + 257)     /* 16: bases (2x8 parity); swm at level 1 */
#define FLG_OFF (BB_OFF + 16)      /* 257 int flags */
#define MSC_OFF (FLG_OFF + 257)    /* [0] len, [1] isb, [2] res(float) */
#define S0_OFF  (MSC_OFF + 3)      /* 3696 = 16*231 (odd-index groups)  */
#define S1_OFF  (S0_OFF + 3696)    /* 3824 = 16*239 (even-index groups) */
#define LDSF    (S1_OFF + 3824)    /* 40949 floats = 163796 B */

#define RES_OFF ((size_t)16)
#define LEN_OFF ((size_t)(16 + NCHART))
#define FB_OFF  ((size_t)(16 + NCHART + BATCH + 16))

__device__ __forceinline__ float fexp2(float x) {
#if __has_builtin(__builtin_amdgcn_exp2f)
    return __builtin_amdgcn_exp2f(x);
#else
    return exp2f(x);
#endif
}

// wave64 max reduce via DPP (VALU pipe), broadcast via readlane 63.
__device__ __forceinline__ float wave_max64(float x) {
    int v = __float_as_int(x);
    int s;
    s = __builtin_amdgcn_update_dpp(v, v, 0x111, 0xf, 0xf, false);
    v = __float_as_int(fmaxf(__int_as_float(v), __int_as_float(s)));
    s = __builtin_amdgcn_update_dpp(v, v, 0x112, 0xf, 0xf, false);
    v = __float_as_int(fmaxf(__int_as_float(v), __int_as_float(s)));
    s = __builtin_amdgcn_update_dpp(v, v, 0x114, 0xf, 0xf, false);
    v = __float_as_int(fmaxf(__int_as_float(v), __int_as_float(s)));
    s = __builtin_amdgcn_update_dpp(v, v, 0x118, 0xf, 0xf, false);
    v = __float_as_int(fmaxf(__int_as_float(v), __int_as_float(s)));
    s = __builtin_amdgcn_update_dpp(v, v, 0x142, 0xa, 0xf, false);
    v = __float_as_int(fmaxf(__int_as_float(v), __int_as_float(s)));
    s = __builtin_amdgcn_update_dpp(v, v, 0x143, 0xc, 0xf, false);
    v = __float_as_int(fmaxf(__int_as_float(v), __int_as_float(s)));
    return __int_as_float(__builtin_amdgcn_readlane(v, 63));
}

__device__ __forceinline__ float rlane(float v, int idx) {
    return __int_as_float(__builtin_amdgcn_readlane(__float_as_int(v), idx));
}

// column start (floats) for width v, v in 1..256
__device__ __forceinline__ int cstart(int v) {
    return 257 * (v - 1) - ((v * (v - 1)) >> 1);
}

// log2-domain score at span [i, j] for type t (0 = ob/constrained, 1 = allv)
// = K2f * (mx + ln(1+e^(mn-mx)))  computed as  K2f*mx + log2(1+2^(K2f*d))
__device__ __forceinline__ float score2_at(const float* __restrict__ logits,
                                           const int* __restrict__ spans_ind,
                                           const void* __restrict__ span_mask,
                                           int isb, int t, int b, int i, int j) {
    size_t sidx = ((size_t)b * NN + i) * NN + j;
    float l0 = logits[2 * sidx];
    float l1 = logits[2 * sidx + 1];
    float mx, mn;
    if (t) {
        mx = fmaxf(l0, l1); mn = fminf(l0, l1);
    } else {
        bool sind = (spans_ind[sidx] == 2);
        bool sm = isb ? (((const unsigned char*)span_mask)[sidx] != 0)
                      : (((const int*)span_mask)[sidx] != 0);
        float s0 = (sm || sind)  ? NEGV : l0;
        float s1 = (sm || !sind) ? NEGV : l1;
        mx = fmaxf(s0, s1); mn = fminf(s0, s1);
    }
    return fmaf(K2f, mx, __log2f(1.f + fexp2(K2f * (mn - mx))));
}

// seed levels 2..9: wave g finalizes level g+2, flag-pipelined, no barriers.
// Border-pair folding j = L/2 .. 1 (pair (j, L-j)); self-pair guard (even L).
__device__ __forceinline__ void seed_levels(
    float* __restrict__ Lc, float* __restrict__ cm, int* flg, int* msc,
    int wave, int lane, int lenv) {
    if (wave >= 8) return;
    const int L = wave + 2;            // 2..9
    const int E = 257 - L;             // >= 248 -> KK = 4
    float m = NEGB;
    float s[4] = {0.f, 0.f, 0.f, 0.f};
    for (int j = L >> 1; j >= 1; --j) {
        const int v = L - j;           // v >= j; cols publish ascending
        if (v >= 2) { while (((volatile int*)flg)[v] == 0) {} }
        asm volatile("" ::: "memory");
        float pm = cm[j] + cm[v];
        float nm = fmaxf(m, pm);
        float sc = fexp2(m - nm), pj = fexp2(pm - nm);
        const int cj = cstart(j), cl = cstart(v);
#pragma unroll
        for (int k = 0; k < 4; ++k) {
            int ge = lane + 64 * k;
            if (ge < E) {
                float tt = Lc[cj + ge] * Lc[cl + ge + j];
                if (j != v) tt += Lc[cl + ge] * Lc[cj + ge + v];
                s[k] = fmaf(s[k], sc, pj * tt);
            }
        }
        m = nm;
    }
    // finalize: a = D + m + log2(s); exact cmax; publish X + cm + flag
    float xa[4];
    float mx = NEGB;
#pragma unroll
    for (int k = 0; k < 4; ++k) {
        int ge = lane + 64 * k;
        float av = NEGB;
        if (ge < E) av = Lc[cstart(L) + ge] + m + __log2f(s[k]);
        xa[k] = av;
        mx = fmaxf(mx, av);
    }
    mx = wave_max64(mx);
#pragma unroll
    for (int k = 0; k < 4; ++k) {
        int ge = lane + 64 * k;
        if (ge < E) Lc[cstart(L) + ge] = fexp2(xa[k] - mx);
    }
    if (lane == 0) {
        cm[L] = mx;
        if (L == lenv) ((float*)msc)[2] = xa[0];
    }
    __threadfence_block();
    asm volatile("" ::: "memory");
    if (lane == 0) ((volatile int*)flg)[L] = 1;
}

// One group (levels W..W+7): chain waves 0..7 finalize; waves 8..15 pre-bulk
// the NEXT group (W+8) into scrW/bbW. KK = ceil((257-W)/64), KK2 for next.
template <int KK, int KK2>
__device__ __forceinline__ void group_olap(
    float* __restrict__ Lc, float* __restrict__ cm, int* flg, int* msc,
    const float* __restrict__ scrR, float* __restrict__ scrW,
    const float* __restrict__ bbR, float* __restrict__ bbW,
    int W, int wave, int lane, int lenv) {
    const int ESR = 257 - W;

    if (wave >= 8) {
        if constexpr (KK2 > 0) {
            // ---- PRE-BULK for group W2 = W+8: 4 pairs x 2 u-splits ----
            const int W2 = W + 8;
            const int ESW = 257 - W2;
            const int p = (wave - 8) >> 1, sp = (wave - 8) & 1;
            const int G0 = 2 * p, G1 = G0 + 1;
            const int L0 = W2 + G0, L1 = W2 + G1;
            const bool has1 = (L1 <= 256);
            const int E0 = 257 - L0;
            const int E1 = has1 ? (257 - L1) : 0;
            const int lo0 = G0 + 9, hi = W2 - 9;   // hi = W-1: cols stable

            float b0 = NEGB, b1 = NEGB;
            for (int uu = lo0 + lane; uu <= hi; uu += 64) {
                float cu = cm[uu];
                b0 = fmaxf(b0, cu + cm[L0 - uu]);
                if (uu >= lo0 + 1) b1 = fmaxf(b1, cu + cm[L1 - uu]);
            }
            b0 = wave_max64(b0);
            b1 = wave_max64(b1);
            if (lane == 0 && sp == 0) { bbW[G0] = b0; bbW[G1] = b1; }

            const int n = hi - lo0 + 1;
            if (n > 0) {
                const int C = (n + 1) >> 1;
                const int ua = lo0 + sp * C;
                const int ub = min(ua + C - 1, hi);
                const int R = ub - ua + 1;       // <= 121

                float su0r, su1r;
                {
                    int u = ua + lane;
                    int uc = (u <= ub) ? u : ub;
                    bool v0 = (lane < R);
                    bool v1 = v0 && has1 && (uc >= lo0 + 1);
                    float e0 = fexp2(cm[uc] + cm[L0 - uc] - b0);
                    float e1 = fexp2(cm[uc] + cm[L1 - uc] - b1);
                    su0r = v0 ? e0 : 0.f;
                    su1r = v1 ? e1 : 0.f;
                }
                float su2r = 0.f, su3r = 0.f;
                if (R > 64) {
                    int u = ua + 64 + lane;
                    int uc = (u <= ub) ? u : ub;
                    bool v0 = (64 + lane < R);
                    bool v1 = v0 && has1;
                    float e0 = fexp2(cm[uc] + cm[L0 - uc] - b0);
                    float e1 = fexp2(cm[uc] + cm[L1 - uc] - b1);
                    su2r = v0 ? e0 : 0.f;
                    su3r = v1 ? e1 : 0.f;
                }

                float a0[KK2], a1[KK2];
#pragma unroll
                for (int k = 0; k < KK2; ++k) { a0[k] = 0.f; a1[k] = 0.f; }

                if (R > 0) {
                    int la  = cstart(ua) + lane;
                    int ra0 = cstart(L0 - ua) + ua + lane;
                    int ra1 = cstart(L1 - ua) + ua + lane;
                    int A  = 257 - ua;
                    int B0 = 257 - (L0 - ua);
                    int B1 = 257 - (L1 - ua);
                    const int R0 = (R < 64) ? R : 64;
#pragma unroll 2
                    for (int idx = 0; idx < R0; ++idx) {
                        float su0 = rlane(su0r, idx);
                        float su1 = rlane(su1r, idx);
#pragma unroll
                        for (int k = 0; k < KK2; ++k) {
                            float lv = Lc[la  + 64 * k];
                            float r0 = Lc[ra0 + 64 * k];
                            float r1 = Lc[ra1 + 64 * k];
                            a0[k] = fmaf(su0 * lv, r0, a0[k]);
                            a1[k] = fmaf(su1 * lv, r1, a1[k]);
                        }
                        la += A; A -= 1;
                        ra0 -= B0; B0 += 1;
                        ra1 -= B1; B1 += 1;
                    }
#pragma unroll 2
                    for (int idx = 64; idx < R; ++idx) {
                        float su0 = rlane(su2r, idx - 64);
                        float su1 = rlane(su3r, idx - 64);
#pragma unroll
                        for (int k = 0; k < KK2; ++k) {
                            float lv = Lc[la  + 64 * k];
                            float r0 = Lc[ra0 + 64 * k];
                            float r1 = Lc[ra1 + 64 * k];
                            a0[k] = fmaf(su0 * lv, r0, a0[k]);
                            a1[k] = fmaf(su1 * lv, r1, a1[k]);
                        }
                        la += A; A -= 1;
                        ra0 -= B0; B0 += 1;
                        ra1 -= B1; B1 += 1;
                    }
                }
#pragma unroll
                for (int k = 0; k < KK2; ++k) {
                    int ge = lane + 64 * k;
                    if (ge < E0) scrW[(2 * G0 + sp) * ESW + ge] = a0[k];
                    if (ge < E1) scrW[(2 * G1 + sp) * ESW + ge] = a1[k];
                }
            }
        }
    } else {
        // ---- CHAIN: wave g finalizes level W+g (fixup + borders) ----
        const int g = wave;
        const int L = W + g;
        if (L <= 256) {
            const int E = 257 - L;
            float m = NEGB;
            float s[KK];
#pragma unroll
            for (int k = 0; k < KK; ++k) s[k] = 0.f;

            if (W >= g + 18) {                  // pre-band existed
                m = bbR[g];
#pragma unroll
                for (int k = 0; k < KK; ++k) {
                    int ge = lane + 64 * k;
                    if (ge < E)
                        s[k] = scrR[(2 * g) * ESR + ge] +
                               scrR[(2 * g + 1) * ESR + ge];
                }
            }

            // fixup bands (operand in previous group; barrier-guaranteed)
            const int b1lo = g + 1, b1hi = min(g + 8, W - 1);
            const int b2lo = max(W - 8, g + 9), b2hi = W - 1;
            float m2 = m;
            for (int u = b1lo; u <= b1hi; ++u) m2 = fmaxf(m2, cm[u] + cm[L - u]);
            for (int u = b2lo; u <= b2hi; ++u) m2 = fmaxf(m2, cm[u] + cm[L - u]);
            {
                float sc = fexp2(m - m2);
#pragma unroll
                for (int k = 0; k < KK; ++k) s[k] *= sc;
                m = m2;
            }
            for (int u = b1lo; u <= b1hi; ++u) {
                float su = fexp2(cm[u] + cm[L - u] - m);
                const int ca = cstart(u), cb = cstart(L - u);
#pragma unroll
                for (int k = 0; k < KK; ++k) {
                    int ge = lane + 64 * k;
                    if (ge < E)
                        s[k] = fmaf(su * Lc[ca + ge], Lc[cb + ge + u], s[k]);
                }
            }
            for (int u = b2lo; u <= b2hi; ++u) {
                float su = fexp2(cm[u] + cm[L - u] - m);
                const int ca = cstart(u), cb = cstart(L - u);
#pragma unroll
                for (int k = 0; k < KK; ++k) {
                    int ge = lane + 64 * k;
                    if (ge < E)
                        s[k] = fmaf(su * Lc[ca + ge], Lc[cb + ge + u], s[k]);
                }
            }

            // borders j=g..1: hoist ancient-col (j<=7) reads above the poll
            for (int j = g; j >= 1; --j) {
                const int v = L - j;
                const int cj = cstart(j), cl = cstart(v);
                float xj0[KK], xj1[KK];
#pragma unroll
                for (int k = 0; k < KK; ++k) {
                    int ge = lane + 64 * k;
                    xj0[k] = (ge < E) ? Lc[cj + ge] : 0.f;
                    xj1[k] = (ge < E) ? Lc[cj + ge + v] : 0.f;
                }
                asm volatile("" ::: "memory");   // keep hoisted loads here
                while (((volatile int*)flg)[v] == 0) {}
                asm volatile("" ::: "memory");
                float pm = cm[j] + cm[v];
                float nm = fmaxf(m, pm);
                float sc = fexp2(m - nm), pj = fexp2(pm - nm);
#pragma unroll
                for (int k = 0; k < KK; ++k) {
                    int ge = lane + 64 * k;
                    if (ge < E) {
                        float tt = xj0[k] * Lc[cl + ge + j] +
                                   Lc[cl + ge] * xj1[k];
                        s[k] = fmaf(s[k], sc, pj * tt);
                    }
                }
                m = nm;
            }

            // finalize: a = D + m + log2(s); exact cmax; publish X + flag
            float xa[KK];
            float mx = NEGB;
#pragma unroll
            for (int k = 0; k < KK; ++k) {
                int ge = lane + 64 * k;
                float av = NEGB;
                if (ge < E) av = Lc[cstart(L) + ge] + m + __log2f(s[k]);
                xa[k] = av;
                mx = fmaxf(mx, av);
            }
            mx = wave_max64(mx);
#pragma unroll
            for (int k = 0; k < KK; ++k) {
                int ge = lane + 64 * k;
                if (ge < E) Lc[cstart(L) + ge] = fexp2(xa[k] - mx);
            }
            if (lane == 0) {
                cm[L] = mx;
                if (L == lenv) ((float*)msc)[2] = xa[0];
            }
            __threadfence_block();
            asm volatile("" ::: "memory");
            if (lane == 0) ((volatile int*)flg)[L] = 1;
        }
    }
    __syncthreads();   // group columns + cm + next-group slots visible
}

template <bool USE_LDS>
__global__ __launch_bounds__(1024) void cyk_kernel(
    const float* __restrict__ logits,     // [B,N,N,2] f32
    const int* __restrict__ spans_ind,    // [B,N,N] i32
    const void* __restrict__ maskspan,    // [B,N,N] bool (byte or i32)
    const void* __restrict__ span_mask,   // [B,N,N] bool
    float* __restrict__ ws) {
    extern __shared__ float lds[];
    const int c = blockIdx.x;
    const int b = c >> 1;
    const int t = c & 1;
    const int tid = threadIdx.x;
    const int wave = tid >> 6, lane = tid & 63;

    float* __restrict__ Lc = USE_LDS ? lds : (ws + FB_OFF + (size_t)c * LDSF);
    float* __restrict__ cm = Lc + CM_OFF;
    float* __restrict__ BB = Lc + BB_OFF;
    int* flg = (int*)(Lc + FLG_OFF);
    int* msc = (int*)(Lc + MSC_OFF);
    float* __restrict__ S0 = Lc + S0_OFF;
    float* __restrict__ S1 = Lc + S1_OFF;

    if (tid == 0) {
        ((float*)msc)[2] = K2f * NEGV;
        unsigned probe = *(const unsigned*)maskspan;
        msc[1] = (probe > 1u) ? 1 : 0;  // byte-packed bools -> 0x01010101
    }
    if (tid < 257) flg[tid] = 0;
    __syncthreads();
    const int isb = msc[1];

    // lens[b]: wave 0 counts 256 mask entries (4/lane), shfl-sum
    if (wave == 0) {
        int cnt = 0;
        for (int q = 0; q < 4; ++q) {
            int j = lane * 4 + q;
            size_t off = (size_t)b * NN * NN + j;
            int v = isb ? (((const unsigned char*)maskspan)[off] ? 1 : 0)
                        : (((const int*)maskspan)[off] ? 1 : 0);
            cnt += v;
        }
        for (int d = 32; d; d >>= 1) cnt += __shfl_xor(cnt, d);
        if (lane == 0) msc[0] = cnt;
    }

    // one-time D-fill: chart col v = j-i+1 holds log2-domain D until level v
    for (int it = 0; it < 64; ++it) {
        int f = (it << 10) + tid;            // over the (i, j) square
        int i = f >> 8, j = f & 255;
        if (j >= i) {
            Lc[cstart(j - i + 1) + i] =
                score2_at(logits, spans_ind, span_mask, isb, t, b, i, j);
        }
    }
    __syncthreads();
    const int lenv = msc[0];

    // level 1: convert col 1 to X with exact cmax[1]
    {
        float a = (tid < NN) ? Lc[tid] : NEGB;
        if (tid == 0 && lenv == 1) ((float*)msc)[2] = a;
        float m = wave_max64(a);
        if (lane == 0) BB[wave] = m;
        __syncthreads();
        float c1 = BB[0];
#pragma unroll
        for (int i = 1; i < 16; ++i) c1 = fmaxf(c1, BB[i]);
        if (tid < NN) Lc[tid] = fexp2(a - c1);
        if (tid == 0) cm[1] = c1;
    }
    __syncthreads();

    // seed levels 2..9 (flag-pipelined, waves 0-7)
    seed_levels(Lc, cm, flg, msc, wave, lane, lenv);
    __syncthreads();

    // groups: W = 10 + 8k; group k reads buf[k&1], writes buf[(k+1)&1]
#define GRP(KA, KB, WV)                                                     \
    {                                                                       \
        const int gk = ((WV) - 10) >> 3;                                    \
        const float* sR = (gk & 1) ? S1 : S0;                               \
        float* sW = (gk & 1) ? S0 : S1;                                     \
        const float* bR = BB + (gk & 1) * 8;                                \
        float* bW = BB + ((gk + 1) & 1) * 8;                                \
        group_olap<KA, KB>(Lc, cm, flg, msc, sR, sW, bR, bW, (WV),          \
                           wave, lane, lenv);                               \
    }
    for (int W = 10; W <= 50; W += 8) GRP(4, 4, W)
    GRP(4, 3, 58)
    for (int W = 66; W <= 114; W += 8) GRP(3, 3, W)
    GRP(3, 2, 122)
    for (int W = 130; W <= 178; W += 8) GRP(2, 2, W)
    GRP(2, 1, 186)
    for (int W = 194; W <= 242; W += 8) GRP(1, 1, W)
    GRP(1, 0, 250)
#undef GRP

    if (tid == 0) {
        int len = msc[0];
        float rres = (len >= 1) ? (((float*)msc)[2] * LN2f) : NEGV;
        ws[RES_OFF + c] = rres;
        if (t == 0) ws[LEN_OFF + b] = (float)len;
    }
}

__global__ __launch_bounds__(64) void finish_kernel(const float* __restrict__ ws,
                                                    float* __restrict__ out) {
    int b = threadIdx.x;  // 0..63
    float diff = ws[RES_OFF + 2 * b + 1] - ws[RES_OFF + 2 * b];
    float len  = ws[LEN_OFF + b];
    for (int d = 32; d > 0; d >>= 1) {
        diff += __shfl_xor(diff, d);
        len  += __shfl_xor(len, d);
    }
    if (b == 0) out[0] = diff / len;
}

extern "C" void kernel_launch(void* const* d_in, const int* in_sizes, int n_in,
                              void* d_out, int out_size, void* d_ws, size_t ws_size,
                              hipStream_t stream) {
    const float* logits    = (const float*)d_in[0];
    const int*   spans_ind = (const int*)d_in[1];
    const void*  maskspan  = d_in[2];
    const void*  span_mask = d_in[3];
    float* ws = (float*)d_ws;

    const size_t shbytes = (size_t)LDSF * sizeof(float);  // 163796 B
    hipError_t e = hipFuncSetAttribute(
        reinterpret_cast<const void*>(&cyk_kernel<true>),
        hipFuncAttributeMaxDynamicSharedMemorySize, (int)shbytes);
    if (e == hipSuccess) {
        hipLaunchKernelGGL(cyk_kernel<true>, dim3(NCHART), dim3(1024), shbytes,
                           stream, logits, spans_ind, maskspan, span_mask, ws);
    } else {
        hipLaunchKernelGGL(cyk_kernel<false>, dim3(NCHART), dim3(1024), 0,
                           stream, logits, spans_ind, maskspan, span_mask, ws);
    }
    hipLaunchKernelGGL(finish_kernel, dim3(1), dim3(64), 0, stream,
                       ws, (float*)d_out);
}